// Round 11
// baseline (175.965 us; speedup 1.0000x reference)
//
#include <hip/hip_runtime.h>
#include <hip/hip_bf16.h>

#define IN_F 4096
#define OUT_F 4096
#define CPN 81
#define OINV 2225   // 81^{-1} mod 4096
#define OB16 2832   // 2225*16 mod 4096: o-step per group

#define BMF 8       // batch rows per block
#define NCH 16      // chunks per block
#define CHUNK 256   // band-starts (and x cols) per chunk
#define SC4 84      // float4 staged per row per chunk (336 cols = 256+80)
#define NLD 672     // BMF*SC4 loads per chunk
#define XSTR 344    // x LDS stride in shorts (8-mult, odd*8 -> bank spread)
#define RSTRF 8     // res stride in shorts (16 B per o-row)

typedef __attribute__((ext_vector_type(4))) float f32x4;
typedef __attribute__((ext_vector_type(8))) short bf16x8;

__device__ __forceinline__ unsigned short f2bf(float f) {
  __hip_bfloat16 h = __float2bfloat16(f);
  return *reinterpret_cast<unsigned short*>(&h);
}
__device__ __forceinline__ float bf2f(unsigned short u) {
  unsigned int v = ((unsigned int)u) << 16;
  return *reinterpret_cast<float*>(&v);
}

// ---- prep: pack weight*mask into MFMA B-fragment order ----
__global__ void prep_wfrag(const float* __restrict__ w,
                           const float* __restrict__ mask,
                           unsigned short* __restrict__ wfrag) {
  int idx = blockIdx.x * 256 + threadIdx.x;   // 49152 threads
  int lane = idx & 63;
  int t = (idx >> 6) % 3;
  int g = idx / 192;
  int n = lane & 15;
  int kg = lane >> 4;
  int s = g * 16 + n;
  int o = (OINV * s) & 4095;
  unsigned short v8[8];
#pragma unroll
  for (int i = 0; i < 8; ++i) {
    int c = 32 * t + 8 * kg + i;
    int j = c - n;
    float v = 0.f;
    if (j >= 0 && j < CPN) {
      int col = (16 * g + c) & 4095;
      v = w[(size_t)o * IN_F + col] * mask[(size_t)o * IN_F + col];
    }
    v8[i] = f2bf(v);
  }
  *reinterpret_cast<bf16x8*>(wfrag + (size_t)idx * 8) =
      *reinterpret_cast<const bf16x8*>(v8);
}

// ---- fused: xl double-buffer, ONE barrier per chunk ----
// loop body: load(q+2)->regs || drain(q+1)->buf^1 || compute(q)<-buf ; barrier
__global__ __launch_bounds__(512, 4) void sc_fused(
    const float* __restrict__ x, const float* __restrict__ bias,
    const unsigned short* __restrict__ wfrag, float* __restrict__ out) {
  __shared__ unsigned short res[4096 * RSTRF];   // 65536 B: [o][row] bf16
  __shared__ unsigned short xl[2][BMF * XSTR];   // 2 x 5504 B

  const int blk = blockIdx.x;        // 0..2047
  const int b0 = blk * BMF;
  const int tid = threadIdx.x;
  const int wave = tid >> 6;         // 0..7
  const int lane = tid & 63;
  const int ln = lane & 15;          // MFMA n index (s offset)
  const int lk = lane >> 4;          // k-group / D row quad
  const int oln = (OINV * ln) & 4095;
  const int q0 = blk & 15;           // stagger chunk order across blocks

  // staging coords: 2 slots (672 loads over 512 threads)
  const int i1 = tid + 512;
  const int row0 = tid / SC4, c40 = tid - row0 * SC4;
  const int row1 = i1 / SC4,  c41 = i1 - row1 * SC4;
  const bool v1 = (i1 < NLD);
  const float* xp0 = x + (size_t)(b0 + row0) * IN_F;
  const float* xp1 = x + (size_t)(b0 + row1) * IN_F;
  const int xo0 = row0 * XSTR + 4 * c40;
  const int xo1 = row1 * XSTR + 4 * c41;

  auto loadx = [&](int q, float4& r0, float4& r1) {
    const int c0 = q * CHUNK;
    r0 = *reinterpret_cast<const float4*>(xp0 + ((c0 + 4 * c40) & 4095));
    if (v1) r1 = *reinterpret_cast<const float4*>(xp1 + ((c0 + 4 * c41) & 4095));
  };
  auto drain = [&](int buf, const float4& r0, const float4& r1) {
    ushort4 h;
    h.x = f2bf(r0.x); h.y = f2bf(r0.y); h.z = f2bf(r0.z); h.w = f2bf(r0.w);
    *reinterpret_cast<ushort4*>(&xl[buf][xo0]) = h;
    if (v1) {
      h.x = f2bf(r1.x); h.y = f2bf(r1.y); h.z = f2bf(r1.z); h.w = f2bf(r1.w);
      *reinterpret_cast<ushort4*>(&xl[buf][xo1]) = h;
    }
  };
  // one 16x16 group: 3 ds_reads + 3 MFMA + res scatter
  auto grp = [&](int g, const unsigned short* ap,
                 bf16x8 b0f, bf16x8 b1f, bf16x8 b2f) {
    bf16x8 a0 = *reinterpret_cast<const bf16x8*>(ap);
    bf16x8 a1 = *reinterpret_cast<const bf16x8*>(ap + 32);
    bf16x8 a2 = *reinterpret_cast<const bf16x8*>(ap + 64);
    f32x4 acc = f32x4{0.f, 0.f, 0.f, 0.f};
    acc = __builtin_amdgcn_mfma_f32_16x16x32_bf16(a0, b0f, acc, 0, 0, 0);
    acc = __builtin_amdgcn_mfma_f32_16x16x32_bf16(a1, b1f, acc, 0, 0, 0);
    acc = __builtin_amdgcn_mfma_f32_16x16x32_bf16(a2, b2f, acc, 0, 0, 0);
    if (lk < 2) {                    // rows 0..7 (8..15 are dups)
      int o = (OB16 * g + oln) & 4095;
      ushort4 h;
      h.x = f2bf(acc[0]); h.y = f2bf(acc[1]);
      h.z = f2bf(acc[2]); h.w = f2bf(acc[3]);
      *reinterpret_cast<ushort4*>(res + o * RSTRF + 4 * lk) = h;
    }
  };
  auto compute = [&](int q, int buf) {
    const int gbase = q * 16 + wave * 2;   // 2 groups per wave per chunk
    const bf16x8* wf = reinterpret_cast<const bf16x8*>(wfrag)
                     + (size_t)gbase * 192 + lane;
    // batch-issue all 6 B-fragment loads (L2-resident)
    bf16x8 w0 = wf[0],   w1 = wf[64],  w2 = wf[128];
    bf16x8 w3 = wf[192], w4 = wf[256], w5 = wf[320];
    const unsigned short* ap = &xl[buf][(ln & 7) * XSTR + 8 * lk + 32 * wave];
    grp(gbase + 0, ap,      w0, w1, w2);
    grp(gbase + 1, ap + 16, w3, w4, w5);
  };

  // prologue: buf0 <- q0, regs B <- q0+1
  float4 A0, A1, B0, B1;
  loadx(q0, A0, A1);
  drain(0, A0, A1);
  loadx((q0 + 1) & 15, B0, B1);
  __syncthreads();

  for (int i = 0; i < NCH; i += 2) {
    const int qa = (q0 + i) & 15;
    const int qb = (q0 + i + 1) & 15;

    if (i + 2 < NCH) loadx((q0 + i + 2) & 15, A0, A1);
    __builtin_amdgcn_sched_barrier(0);
    drain(1, B0, B1);                 // q(i+1) -> buf1 (compute reads buf0)
    compute(qa, 0);
    __syncthreads();

    if (i + 3 < NCH) loadx((q0 + i + 3) & 15, B0, B1);
    __builtin_amdgcn_sched_barrier(0);
    if (i + 2 < NCH) drain(0, A0, A1);  // q(i+2) -> buf0 (compute reads buf1)
    compute(qb, 1);
    __syncthreads();
  }

  // ---- epilogue: out[b0+r][o] = res[o][r] + bias[o] ----
  // lane = (ol, j): b32 read at byte 16o+4j -> bank 4(o&7)+j: 2-way max.
  const int j  = lane & 3;          // row pair 2j, 2j+1
  const int ol = lane >> 2;         // 0..15 consecutive o
#pragma unroll 4
  for (int it = 0; it < 32; ++it) {
    int o = it * 128 + wave * 16 + ol;
    unsigned int v = *reinterpret_cast<const unsigned int*>(res + o * RSTRF + 2 * j);
    float b = bias[o];
    float lo = bf2f((unsigned short)(v & 0xffff)) + b;
    float hi = bf2f((unsigned short)(v >> 16)) + b;
    size_t base = (size_t)(b0 + 2 * j) * OUT_F + o;
    out[base]         = lo;
    out[base + OUT_F] = hi;
  }
}

extern "C" void kernel_launch(void* const* d_in, const int* in_sizes, int n_in,
                              void* d_out, int out_size, void* d_ws, size_t ws_size,
                              hipStream_t stream) {
  const float* x    = (const float*)d_in[0];
  const float* w    = (const float*)d_in[1];
  const float* bias = (const float*)d_in[2];
  const float* mask = (const float*)d_in[3];
  float* out = (float*)d_out;

  unsigned short* wfrag = (unsigned short*)d_ws;   // 786432 B

  const int B = in_sizes[0] / IN_F;                // 16384

  prep_wfrag<<<192, 256, 0, stream>>>(w, mask, wfrag);
  sc_fused<<<B / BMF, 512, 0, stream>>>(x, bias, wfrag, out);
}

// Round 12
// 173.900 us; speedup vs baseline: 1.0119x; 1.0119x over previous
//
#include <hip/hip_runtime.h>
#include <hip/hip_bf16.h>

#define IN_F 4096
#define OUT_F 4096
#define CPN 81
#define OINV 2225   // 81^{-1} mod 4096
#define OB16 2832   // 2225*16 mod 4096: o-step per group

#define BMF 16      // batch rows per block
#define NCH 16      // chunks per block
#define CHUNK 256   // band-starts (and x cols) per chunk
#define SC4 84      // float4 staged per row per chunk (336 cols = 256+80)
#define NLD 1344    // BMF*SC4 loads per chunk
#define XSTR 344    // x LDS stride in shorts
#define NTHR 1024

typedef __attribute__((ext_vector_type(4))) float f32x4;
typedef __attribute__((ext_vector_type(8))) short bf16x8;

__device__ __forceinline__ unsigned short f2bf(float f) {
  __hip_bfloat16 h = __float2bfloat16(f);
  return *reinterpret_cast<unsigned short*>(&h);
}
__device__ __forceinline__ float bf2f(unsigned short u) {
  unsigned int v = ((unsigned int)u) << 16;
  return *reinterpret_cast<float*>(&v);
}

struct WF3 { bf16x8 w0, w1, w2; };   // one group's 3 B-fragments (static names)

// ---- prep: pack weight*mask into MFMA B-fragment order ----
__global__ void prep_wfrag(const float* __restrict__ w,
                           const float* __restrict__ mask,
                           unsigned short* __restrict__ wfrag) {
  int idx = blockIdx.x * 256 + threadIdx.x;   // 49152 threads
  int lane = idx & 63;
  int t = (idx >> 6) % 3;
  int g = idx / 192;
  int n = lane & 15;
  int kg = lane >> 4;
  int s = g * 16 + n;
  int o = (OINV * s) & 4095;
  unsigned short v8[8];
#pragma unroll
  for (int i = 0; i < 8; ++i) {
    int c = 32 * t + 8 * kg + i;
    int j = c - n;
    float v = 0.f;
    if (j >= 0 && j < CPN) {
      int col = (16 * g + c) & 4095;
      v = w[(size_t)o * IN_F + col] * mask[(size_t)o * IN_F + col];
    }
    v8[i] = f2bf(v);
  }
  *reinterpret_cast<bf16x8*>(wfrag + (size_t)idx * 8) =
      *reinterpret_cast<const bf16x8*>(v8);
}

// ---- fused: 16 rows x all 4096 outputs, one 1024-thread block ----
__global__ __launch_bounds__(NTHR, 4) void sc_fused(
    const float* __restrict__ x, const float* __restrict__ bias,
    const unsigned short* __restrict__ wfrag, float* __restrict__ out) {
  __shared__ unsigned short res[4096 * BMF];     // 131072 B: [o][row] bf16
  __shared__ unsigned short xl[2][BMF * XSTR];   // 2 x 11008 B

  const int blk = blockIdx.x;        // 0..1023
  const int b0 = blk * BMF;
  const int tid = threadIdx.x;
  const int wave = tid >> 6;         // 0..15
  const int lane = tid & 63;
  const int ln = lane & 15;          // A row (batch) / D col (s offset)
  const int lk = lane >> 4;          // k-group / D row quad
  const int oln = (OINV * ln) & 4095;
  const int q0 = blk & 15;           // stagger chunk order across blocks

  // staging coords: 2 slots (1344 loads over 1024 threads)
  const int i1 = tid + NTHR;
  const int row0 = tid / SC4, c40 = tid - row0 * SC4;
  const int row1 = i1 / SC4,  c41 = i1 - row1 * SC4;
  const bool v1 = (i1 < NLD);
  const float* xp0 = x + (size_t)(b0 + row0) * IN_F;
  const float* xp1 = x + (size_t)(b0 + (v1 ? row1 : 0)) * IN_F;
  const int xo0 = row0 * XSTR + 4 * c40;
  const int xo1 = (v1 ? row1 : 0) * XSTR + 4 * (v1 ? c41 : 0);

  auto loadx = [&](int q, float4& r0, float4& r1) {
    const int c0 = q * CHUNK;
    r0 = *reinterpret_cast<const float4*>(xp0 + ((c0 + 4 * c40) & 4095));
    if (v1) r1 = *reinterpret_cast<const float4*>(xp1 + ((c0 + 4 * c41) & 4095));
  };
  auto drain = [&](int buf, const float4& r0, const float4& r1) {
    ushort4 h;
    h.x = f2bf(r0.x); h.y = f2bf(r0.y); h.z = f2bf(r0.z); h.w = f2bf(r0.w);
    *reinterpret_cast<ushort4*>(&xl[buf][xo0]) = h;
    if (v1) {
      h.x = f2bf(r1.x); h.y = f2bf(r1.y); h.z = f2bf(r1.z); h.w = f2bf(r1.w);
      *reinterpret_cast<ushort4*>(&xl[buf][xo1]) = h;
    }
  };
  auto loadwf = [&](int q) -> WF3 {
    const int g = q * 16 + wave;
    const bf16x8* wf = reinterpret_cast<const bf16x8*>(wfrag)
                     + (size_t)g * 192 + lane;
    WF3 r; r.w0 = wf[0]; r.w1 = wf[64]; r.w2 = wf[128];
    return r;
  };
  auto compute = [&](int q, int buf, const WF3& W) {
    const int g = q * 16 + wave;     // one group per wave per chunk
    const unsigned short* ap = &xl[buf][ln * XSTR + 16 * wave + 8 * lk];
    bf16x8 a0 = *reinterpret_cast<const bf16x8*>(ap);
    bf16x8 a1 = *reinterpret_cast<const bf16x8*>(ap + 32);
    bf16x8 a2 = *reinterpret_cast<const bf16x8*>(ap + 64);
    f32x4 acc = f32x4{0.f, 0.f, 0.f, 0.f};
    acc = __builtin_amdgcn_mfma_f32_16x16x32_bf16(a0, W.w0, acc, 0, 0, 0);
    acc = __builtin_amdgcn_mfma_f32_16x16x32_bf16(a1, W.w1, acc, 0, 0, 0);
    acc = __builtin_amdgcn_mfma_f32_16x16x32_bf16(a2, W.w2, acc, 0, 0, 0);
    // D: row = 4*lk + r (batch), col = ln -> output o
    const int o = (OB16 * g + oln) & 4095;
    ushort4 h;
    h.x = f2bf(acc[0]); h.y = f2bf(acc[1]);
    h.z = f2bf(acc[2]); h.w = f2bf(acc[3]);
    *reinterpret_cast<ushort4*>(res + o * BMF + 4 * lk) = h;
  };

  // prologue
  float4 xA0, xA1, xB0, xB1;
  WF3 Wa = loadwf(q0);
  WF3 Wb = loadwf((q0 + 1) & 15);
  loadx(q0, xA0, xA1);
  drain(0, xA0, xA1);
  loadx((q0 + 1) & 15, xB0, xB1);
  __syncthreads();

  for (int i = 0; i < NCH; i += 2) {
    const int qa = (q0 + i) & 15;
    const int qb = (q0 + i + 1) & 15;

    if (i + 2 < NCH) loadx((q0 + i + 2) & 15, xA0, xA1);
    __builtin_amdgcn_sched_barrier(0);
    drain(1, xB0, xB1);                    // q(i+1) -> buf1; compute reads buf0
    compute(qa, 0, Wa);
    if (i + 2 < NCH) Wa = loadwf((q0 + i + 2) & 15);   // used 2 phases later
    __syncthreads();

    if (i + 3 < NCH) loadx((q0 + i + 3) & 15, xB0, xB1);
    __builtin_amdgcn_sched_barrier(0);
    if (i + 2 < NCH) drain(0, xA0, xA1);   // q(i+2) -> buf0; compute reads buf1
    compute(qb, 1, Wb);
    if (i + 3 < NCH) Wb = loadwf((q0 + i + 3) & 15);
    __syncthreads();
  }

  // ---- epilogue: out[b0+r][o] = res[o][r] + bias[o], full 64 B lines ----
  // lane = (jj, ln16): rows {2jj,2jj+1,8+2jj,9+2jj}, 16 consecutive o.
  const int ln16 = lane & 15;
  const int jj = lane >> 4;          // 0..3
#pragma unroll 4
  for (int it = 0; it < 16; ++it) {
    int o = it * 256 + wave * 16 + ln16;
    unsigned int v0 = *reinterpret_cast<const unsigned int*>(res + o * BMF + 2 * jj);
    unsigned int v1 = *reinterpret_cast<const unsigned int*>(res + o * BMF + 8 + 2 * jj);
    float b = bias[o];
    size_t base = (size_t)(b0 + 2 * jj) * OUT_F + o;
    out[base]                       = bf2f((unsigned short)(v0 & 0xffff)) + b;
    out[base + OUT_F]               = bf2f((unsigned short)(v0 >> 16)) + b;
    out[base + 8 * (size_t)OUT_F]   = bf2f((unsigned short)(v1 & 0xffff)) + b;
    out[base + 9 * (size_t)OUT_F]   = bf2f((unsigned short)(v1 >> 16)) + b;
  }
}

extern "C" void kernel_launch(void* const* d_in, const int* in_sizes, int n_in,
                              void* d_out, int out_size, void* d_ws, size_t ws_size,
                              hipStream_t stream) {
  const float* x    = (const float*)d_in[0];
  const float* w    = (const float*)d_in[1];
  const float* bias = (const float*)d_in[2];
  const float* mask = (const float*)d_in[3];
  float* out = (float*)d_out;

  unsigned short* wfrag = (unsigned short*)d_ws;   // 786432 B

  const int B = in_sizes[0] / IN_F;                // 16384

  prep_wfrag<<<192, 256, 0, stream>>>(w, mask, wfrag);
  sc_fused<<<B / BMF, NTHR, 0, stream>>>(x, bias, wfrag, out);
}